// Round 8
// baseline (728.275 us; speedup 1.0000x reference)
//
#include <hip/hip_runtime.h>
#include <math.h>

// VectorQuantizer — bit-exact emulation of the numpy fp32 reference (proven R2-R7):
//   d[n,k] = fl32( fl32(x2[n]+c2[k]) - fl32(2 * fl32(exact_fp64_dot)) ), first argmin.
// R7 was LDS-pipe-bound: the x-operand was BROADCAST from LDS (16 ds_read_b128 per
// wave per row for 256B useful -> ~164us of LDS unit). R8: the wave-uniform x goes
// through SGPRs instead. in[b,c,h,w0..w0+15] is contiguous 64B -> one s_load per
// dim step; hot loop = 16 v_fmac(acc[r], s_x[r], v_cb[c]) per step, ZERO LDS, SMEM
// on the parallel scalar pipe. Thread owns code k (cbv[64] regs) + 16 row accs.
// Selection: s_ek materialized once, tree block-min, register filter, exact fp64
// resolve (R2 arithmetic) + packed u64 atomicMin => reference first-argmin.

#define N_CODES   512
#define CODE_DIM  64
#define CH_STRIDE 4096                      // floats between channels
#define B_STRIDE  (CODE_DIM * CH_STRIDE)    // floats between batches
#define RPB       16                        // rows per block (w0 = quarter*16)
#define THR       1.2e-4f                   // >= 2*(ref rounding + fast-dot error)

// numpy pairwise_sum for n=64 (loops.c.src) — setup kernel only.
__device__ __forceinline__ float np_pairwise_sum64(const float* a) {
    float r[8];
#pragma unroll
    for (int j = 0; j < 8; ++j) r[j] = a[j];
#pragma unroll
    for (int i = 8; i < 64; i += 8) {
#pragma unroll
        for (int j = 0; j < 8; ++j) r[j] = __fadd_rn(r[j], a[i + j]);
    }
    return __fadd_rn(__fadd_rn(__fadd_rn(r[0], r[1]), __fadd_rn(r[2], r[3])),
                     __fadd_rn(__fadd_rn(r[4], r[5]), __fadd_rn(r[6], r[7])));
}

__global__ void vq_setup_kernel(const float* __restrict__ cb, float* __restrict__ c2) {
    const int k = blockIdx.x * blockDim.x + threadIdx.x;
    if (k < N_CODES) {
        const float* row = cb + k * CODE_DIM;
        float sq[CODE_DIM];
#pragma unroll
        for (int j = 0; j < CODE_DIM; ++j) sq[j] = __fmul_rn(row[j], row[j]);
        c2[k] = np_pairwise_sum64(sq);
    }
}

__global__ __launch_bounds__(512, 2)
void vq_main_kernel(const float* __restrict__ in,
                    const float* __restrict__ cb,
                    const float* __restrict__ c2g,
                    float* __restrict__ out) {
    __shared__ float s_ek[RPB][N_CODES];    // 32 KB: ek per (row, code)
    __shared__ float s_p[RPB][33];          // partial mins (+1 pad: conflict-free)
    __shared__ float s_bmin[RPB];
    __shared__ float s_x2e[RPB];            // numpy-exact x2 per row
    __shared__ unsigned long long s_res[RPB];

    const int tid  = threadIdx.x;           // == owned code k
    const int lane = tid & 63;
    const int wid  = tid >> 6;              // 0..7
    const int gw   = blockIdx.x >> 2;       // (b,h) group
    const int q    = blockIdx.x & 3;        // row quarter
    const int w0   = q * RPB;

    // Block-uniform base: x[n=w][c] = src[c*CH_STRIDE + w]
    const float* src = in + (size_t)(gw >> 6) * B_STRIDE + (size_t)(gw & 63) * 64;

    // --- numpy-exact x2 for this block's 16 rows (R5-proven rolling order) ---
    if (tid < RPB) {
        const float* xr = src + w0 + tid;   // lanes 0..15 -> w coalesced
        float r[8];
#pragma unroll
        for (int j = 0; j < 8; ++j) {
            const float v = xr[(size_t)j * CH_STRIDE];
            r[j] = __fmul_rn(v, v);
        }
#pragma unroll
        for (int i = 8; i < 64; i += 8) {
#pragma unroll
            for (int j = 0; j < 8; ++j) {
                const float v = xr[(size_t)(i + j) * CH_STRIDE];
                r[j] = __fadd_rn(r[j], __fmul_rn(v, v));
            }
        }
        s_x2e[tid] = __fadd_rn(
            __fadd_rn(__fadd_rn(r[0], r[1]), __fadd_rn(r[2], r[3])),
            __fadd_rn(__fadd_rn(r[4], r[5]), __fadd_rn(r[6], r[7])));
        s_res[tid] = ~0ull;
    }

    // --- Own codebook row -> 64 VGPRs ----------------------------------------
    float cbv[CODE_DIM];
    {
        const float4* cb4 = (const float4*)(cb + (size_t)tid * CODE_DIM);
#pragma unroll
        for (int jj = 0; jj < 16; ++jj) {
            const float4 v = cb4[jj];
            cbv[4 * jj + 0] = v.x; cbv[4 * jj + 1] = v.y;
            cbv[4 * jj + 2] = v.z; cbv[4 * jj + 3] = v.w;
        }
    }
    const float c2v = c2g[tid];

    // --- Hot loop: per dim c, 64B uniform s_load (scalar pipe) + 16 v_fmac ---
    float acc[RPB];
#pragma unroll
    for (int r = 0; r < RPB; ++r) acc[r] = 0.f;

    const float* xbase = src + w0;          // uniform: rows w0..w0+15 contiguous
#pragma unroll
    for (int c = 0; c < CODE_DIM; ++c) {
        const float4* xp = (const float4*)(xbase + (size_t)c * CH_STRIDE);
        const float4 v0 = xp[0], v1 = xp[1], v2 = xp[2], v3 = xp[3];
        const float  cc = cbv[c];
        acc[ 0] = fmaf(v0.x, cc, acc[ 0]);  acc[ 1] = fmaf(v0.y, cc, acc[ 1]);
        acc[ 2] = fmaf(v0.z, cc, acc[ 2]);  acc[ 3] = fmaf(v0.w, cc, acc[ 3]);
        acc[ 4] = fmaf(v1.x, cc, acc[ 4]);  acc[ 5] = fmaf(v1.y, cc, acc[ 5]);
        acc[ 6] = fmaf(v1.z, cc, acc[ 6]);  acc[ 7] = fmaf(v1.w, cc, acc[ 7]);
        acc[ 8] = fmaf(v2.x, cc, acc[ 8]);  acc[ 9] = fmaf(v2.y, cc, acc[ 9]);
        acc[10] = fmaf(v2.z, cc, acc[10]);  acc[11] = fmaf(v2.w, cc, acc[11]);
        acc[12] = fmaf(v3.x, cc, acc[12]);  acc[13] = fmaf(v3.y, cc, acc[13]);
        acc[14] = fmaf(v3.z, cc, acc[14]);  acc[15] = fmaf(v3.w, cc, acc[15]);
    }

    // ek[r] = c2[k] - 2*dot (x2 shift is argmin-invariant); materialize.
#pragma unroll
    for (int r = 0; r < RPB; ++r) {
        acc[r] = __fmaf_rn(-2.0f, acc[r], c2v);
        s_ek[r][tid] = acc[r];              // lanes consecutive: conflict-free
    }
    __syncthreads();

    // --- Block-min per row: stride-32 partials (2-way bank alias = free) -----
    {
        const int r = tid >> 5, g = tid & 31;
        float m = s_ek[r][g];
#pragma unroll
        for (int i = 1; i < 16; ++i) m = fminf(m, s_ek[r][g + 32 * i]);
        s_p[r][g] = m;
    }
    __syncthreads();
    if (tid < RPB) {
        float m = s_p[tid][0];
#pragma unroll
        for (int g = 1; g < 32; ++g) m = fminf(m, s_p[tid][g]);
        s_bmin[tid] = m;
    }
    __syncthreads();

    // --- Exact resolve of near-best (bit-identical R2 arithmetic) ------------
#pragma unroll 1
    for (int r = 0; r < RPB; ++r) {
        if (acc[r] <= s_bmin[r] + THR) {    // capture superset of exact argmin
            const float* xr = src + w0 + r;
            double b0 = 0.0, b1 = 0.0, b2 = 0.0, b3 = 0.0;
#pragma unroll
            for (int j = 0; j < CODE_DIM; j += 4) {
                b0 = fma((double)cbv[j + 0], (double)xr[(size_t)(j + 0) * CH_STRIDE], b0);
                b1 = fma((double)cbv[j + 1], (double)xr[(size_t)(j + 1) * CH_STRIDE], b1);
                b2 = fma((double)cbv[j + 2], (double)xr[(size_t)(j + 2) * CH_STRIDE], b2);
                b3 = fma((double)cbv[j + 3], (double)xr[(size_t)(j + 3) * CH_STRIDE], b3);
            }
            const double dot64 = (b0 + b1) + (b2 + b3);
            const float  ein   = (float)dot64;
            const float  tmp   = __fadd_rn(s_x2e[r], c2v);
            const float  dk    = __fsub_rn(tmp, __fmul_rn(2.0f, ein));
            atomicMin(&s_res[r],
                      ((unsigned long long)__float_as_uint(dk) << 32) | (unsigned)tid);
        }
    }
    __syncthreads();

    // --- Output: wave wid writes rows wid*2, wid*2+1 (coalesced 256B) --------
    const size_t n0 = (size_t)gw * 64 + w0;
#pragma unroll 1
    for (int rr = 0; rr < 2; ++rr) {
        const int row = wid * 2 + rr;
        const int bi  = (int)(s_res[row] & 0xFFFFFFFFull);
        out[(n0 + row) * CODE_DIM + lane] = cb[(size_t)bi * CODE_DIM + lane];
    }
}

extern "C" void kernel_launch(void* const* d_in, const int* in_sizes, int n_in,
                              void* d_out, int out_size, void* d_ws, size_t ws_size,
                              hipStream_t stream) {
    const float* in  = (const float*)d_in[0];   // (16,64,64,64) fp32
    const float* cb  = (const float*)d_in[1];   // (512,64) fp32
    float*       out = (float*)d_out;           // (16,64,64,64) fp32
    float*       c2  = (float*)d_ws;            // 512 floats scratch

    vq_setup_kernel<<<dim3(2), dim3(256), 0, stream>>>(cb, c2);
    // 4096 blocks = 1024 (b,h) groups x 4 row-quarters; 512 threads (code = tid).
    vq_main_kernel<<<dim3(4096), dim3(512), 0, stream>>>(in, cb, c2, out);
}

// Round 9
// 242.267 us; speedup vs baseline: 3.0061x; 3.0061x over previous
//
#include <hip/hip_runtime.h>
#include <math.h>

// VectorQuantizer — bit-exact emulation of the numpy fp32 reference (proven R2-R8):
//   d[n,k] = fl32( fl32(x2[n]+c2[k]) - fl32(2 * fl32(exact_fp64_dot)) ), first argmin.
// R6 (184us) had the right structure: lane=row, wave-uniform codebook row via
// s_load (SGPR=96), x[64] in VGPRs. Its limiter was occupancy: 4-wave blocks on a
// 1024-block grid -> ~12 waves/CU, too few to hide the per-code s_load chain
// (VALUBusy 30%). R8 proved x-side scalarization can't be forced (compiler kept
// per-lane broadcast loads; SGPR=32, 683us). R9 = R6 with 8-wave blocks, 64-code
// chunks per wave, CAP=4 (16KB LDS) -> 3 blocks/CU = 24 waves/CU, 2x latency hiding.

#define N_CODES   512
#define CODE_DIM  64
#define CH_STRIDE 4096                      // floats between channels
#define B_STRIDE  (CODE_DIM * CH_STRIDE)    // floats between batches
#define N_GW      1024                      // (b,h) row-groups
#define NWAVE     8                         // waves per block
#define KCHUNK    (N_CODES / NWAVE)         // 64 codes per wave
#define CAP       4                         // candidate buffer per lane

// numpy pairwise_sum for n=64 (loops.c.src) — setup kernel only.
__device__ __forceinline__ float np_pairwise_sum64(const float* a) {
    float r[8];
#pragma unroll
    for (int j = 0; j < 8; ++j) r[j] = a[j];
#pragma unroll
    for (int i = 8; i < 64; i += 8) {
#pragma unroll
        for (int j = 0; j < 8; ++j) r[j] = __fadd_rn(r[j], a[i + j]);
    }
    return __fadd_rn(__fadd_rn(__fadd_rn(r[0], r[1]), __fadd_rn(r[2], r[3])),
                     __fadd_rn(__fadd_rn(r[4], r[5]), __fadd_rn(r[6], r[7])));
}

__global__ void vq_setup_kernel(const float* __restrict__ cb, float* __restrict__ c2) {
    const int k = blockIdx.x * blockDim.x + threadIdx.x;
    if (k < N_CODES) {
        const float* row = cb + k * CODE_DIM;
        float sq[CODE_DIM];
#pragma unroll
        for (int j = 0; j < CODE_DIM; ++j) sq[j] = __fmul_rn(row[j], row[j]);
        c2[k] = np_pairwise_sum64(sq);
    }
}

// Exact dk — identical arithmetic to the R2 kernel that passed.
__device__ __forceinline__ float exact_dk(const float* __restrict__ cb,
                                          const float* __restrict__ c2,
                                          const float (&x)[CODE_DIM], float x2, int k) {
    const float* crow = cb + (size_t)k * CODE_DIM;
    double a0 = 0.0, a1 = 0.0, a2 = 0.0, a3 = 0.0;
#pragma unroll
    for (int j = 0; j < CODE_DIM; j += 4) {
        a0 = fma((double)crow[j + 0], (double)x[j + 0], a0);
        a1 = fma((double)crow[j + 1], (double)x[j + 1], a1);
        a2 = fma((double)crow[j + 2], (double)x[j + 2], a2);
        a3 = fma((double)crow[j + 3], (double)x[j + 3], a3);
    }
    const double dot = (a0 + a1) + (a2 + a3);
    const float  ein = (float)dot;
    const float  tmp = __fadd_rn(x2, c2[k]);
    return __fsub_rn(tmp, __fmul_rn(2.0f, ein));
}

// One block per (b,h), 8 waves. lane = w (coalesced 256B channel loads). Wave wid
// scans codes [k0, k0+64) with k0 in an SGPR -> codebook rows via s_load.
__global__ __launch_bounds__(512, 2)
void vq_main_kernel(const float* __restrict__ in,
                    const float* __restrict__ cb,
                    const float* __restrict__ c2,
                    float* __restrict__ out) {
    __shared__ float s_cdk[CAP][512];   // [entry][thread]: conflict-free, 8 KB
    __shared__ int   s_cki[CAP][512];   // 8 KB
    __shared__ float s_rb[NWAVE][64];   // per-wave chunk winner dk, 2 KB
    __shared__ int   s_ri[NWAVE][64];   // per-wave chunk winner k,  2 KB

    const int tid  = threadIdx.x;
    const int lane = tid & 63;
    const int wid  = tid >> 6;          // 0..7 -> k-chunk (wave-uniform in fact)
    const int gw   = blockIdx.x;        // 0..1023
    const int b    = gw >> 6;
    const int h    = gw & 63;

    // x[0..63] in VGPRs (stride-4096 loads, coalesced across lanes; the 8 waves
    // read the same lines -> L1 hits after the first).
    const float* xin = in + (size_t)b * B_STRIDE + (size_t)h * 64 + lane;
    float x[CODE_DIM];
#pragma unroll
    for (int c = 0; c < CODE_DIM; ++c) x[c] = xin[(size_t)c * CH_STRIDE];

    // x2 = np.sum(x*x) in numpy pairwise order, rolling 8 accumulators (R5-proven).
    float r[8];
#pragma unroll
    for (int j = 0; j < 8; ++j) r[j] = __fmul_rn(x[j], x[j]);
#pragma unroll
    for (int i = 8; i < 64; i += 8) {
#pragma unroll
        for (int j = 0; j < 8; ++j)
            r[j] = __fadd_rn(r[j], __fmul_rn(x[i + j], x[i + j]));
    }
    const float x2 = __fadd_rn(
        __fadd_rn(__fadd_rn(r[0], r[1]), __fadd_rn(r[2], r[3])),
        __fadd_rn(__fadd_rn(r[4], r[5]), __fadd_rn(r[6], r[7])));

    // k0 in an SGPR (readfirstlane is an identity on the wave-uniform wid) ->
    // crow provably uniform -> s_load path, x[] stays in VGPRs (R6-proven).
    const int k0 = __builtin_amdgcn_readfirstlane(wid) * KCHUNK;

    // --- Pass 1: fp32 fast scan of this wave's 64-code chunk -----------------
    // Capture any k with dk_fast <= chunk_best + thr, thr = 4.5*ulp(best)+8e-6
    // (>= 2*(fast-scan error) incl. binade edge) => exact chunk argmin captured.
    float best = INFINITY, cut = INFINITY;
    int   count = 0, overflow = 0;

#pragma unroll 2
    for (int kk = 0; kk < KCHUNK; ++kk) {
        const int k = k0 + kk;
        const float* crow = cb + (size_t)k * CODE_DIM;
        float a0 = 0.f, a1 = 0.f, a2 = 0.f, a3 = 0.f;
#pragma unroll
        for (int j = 0; j < CODE_DIM; j += 4) {
            a0 = fmaf(x[j + 0], crow[j + 0], a0);
            a1 = fmaf(x[j + 1], crow[j + 1], a1);
            a2 = fmaf(x[j + 2], crow[j + 2], a2);
            a3 = fmaf(x[j + 3], crow[j + 3], a3);
        }
        const float dot = __fadd_rn(__fadd_rn(a0, a1), __fadd_rn(a2, a3));
        const float dk  = __fsub_rn(__fadd_rn(x2, c2[k]), __fmul_rn(2.0f, dot));

        const bool ins = (dk <= cut);   // old cut: conservative superset
        if (dk < best) {
            best = dk;
            const float g = __uint_as_float(__float_as_uint(best) & 0xFF800000u)
                            * 1.1920929e-7f;          // ulp(best)
            cut = __fadd_rn(best, __fmaf_rn(4.5f, g, 8e-6f));
        }
        if (ins) {
            if (count == CAP) {         // compact: drop entries above current cut
                int nc = 0;
#pragma unroll 1
                for (int i = 0; i < CAP; ++i) {
                    const float d  = s_cdk[i][tid];
                    const int   ki = s_cki[i][tid];
                    if (d <= cut) { s_cdk[nc][tid] = d; s_cki[nc][tid] = ki; ++nc; }
                }
                count = nc;
            }
            if (count < CAP) {
                s_cdk[count][tid] = dk;
                s_cki[count][tid] = k;
                ++count;
            } else {
                overflow = 1;
            }
        }
    }

    // --- Pass 2: exact re-resolution of this chunk's candidates --------------
    float ex_best = INFINITY;
    int   bi = k0;
#pragma unroll 1
    for (int i = 0; i < count; ++i) {
        const int   k  = s_cki[i][tid];
        const float dk = exact_dk(cb, c2, x, x2, k);
        if (dk < ex_best) { ex_best = dk; bi = k; }   // ascending k => first-min
    }
    if (__builtin_amdgcn_ballot_w64(overflow != 0)) { // ~never: exact rescan of chunk
        if (overflow) {
            ex_best = INFINITY; bi = k0;
#pragma unroll 1
            for (int kk = 0; kk < KCHUNK; ++kk) {
                const float dk = exact_dk(cb, c2, x, x2, k0 + kk);
                if (dk < ex_best) { ex_best = dk; bi = k0 + kk; }
            }
        }
    }

    // --- Combine the 8 chunk winners (min dk; ties -> lower chunk => lower k) -
    s_rb[wid][lane] = ex_best;
    s_ri[wid][lane] = bi;
    __syncthreads();
    float fb = s_rb[0][lane];
    int   fi = s_ri[0][lane];
#pragma unroll
    for (int w = 1; w < NWAVE; ++w) {
        const float d  = s_rb[w][lane];
        const int   i2 = s_ri[w][lane];
        if (d < fb) { fb = d; fi = i2; }   // strict < keeps earliest chunk on ties
    }

    // --- Output: each wave writes 8 of the 64 rows (coalesced 256B each) -----
    const size_t n0 = (size_t)gw * 64;
#pragma unroll 1
    for (int rr = 0; rr < 8; ++rr) {
        const int row  = wid * 8 + rr;
        const int idxr = __shfl(fi, row, 64);
        out[(n0 + row) * CODE_DIM + lane] = cb[(size_t)idxr * CODE_DIM + lane];
    }
}

extern "C" void kernel_launch(void* const* d_in, const int* in_sizes, int n_in,
                              void* d_out, int out_size, void* d_ws, size_t ws_size,
                              hipStream_t stream) {
    const float* in  = (const float*)d_in[0];   // (16,64,64,64) fp32
    const float* cb  = (const float*)d_in[1];   // (512,64) fp32
    float*       out = (float*)d_out;           // (16,64,64,64) fp32
    float*       c2  = (float*)d_ws;            // 512 floats scratch

    vq_setup_kernel<<<dim3(2), dim3(256), 0, stream>>>(cb, c2);
    vq_main_kernel<<<dim3(N_GW), dim3(512), 0, stream>>>(in, cb, c2, out);
}